// Round 5
// baseline (466.812 us; speedup 1.0000x reference)
//
#include <hip/hip_runtime.h>

// Problem constants (fixed by setup_inputs)
#define BQ   4
#define CQ   2
#define EQ   256
#define LQ   16000
#define WQ   40
#define STEP 20
#define TQ   ((LQ - 1) * STEP + WQ)   // 320020
#define TLF  63                       // owned-frame pitch per block (64 computed, 1 overlap)
#define OWN  (TLF * STEP)             // 1260 owned output samples per block
#define NBX  254                      // 254 * 1260 = 320040 >= 320020
#define NH   8                        // e-octants (channels merged into each thread)
#define EH   (EQ / NH)                // 32 e's per thread
#define NCP  2                        // LDS accumulation copies (one per octant quad)
#define SPAN (TLF * STEP + WQ + STEP) // 1320 floats per (copy, c)
#define BFL  (EQ * WQ)                // 10240 basis floats (40 KB)

// Pre-kernel: transpose basis [W][E] -> wsT [E][W] (fp32, rows contiguous)
// so the decoder can stage e-rows into LDS with coalesced float4 loads.
__global__ void transpose_basis_kernel(const float* __restrict__ basis,
                                       float* __restrict__ wsT) {
    int i = blockIdx.x * 256 + threadIdx.x;
    if (i < EQ * WQ) {
        int e = i / WQ;
        int w = i - e * WQ;
        wsT[i] = basis[w * EQ + e];
    }
}

// One block: 512 threads = 8 e-octants (h) x 64 frames (ll); both channels per
// thread. KEY CHANGE vs rounds 0-4: the basis lives in LDS, not SGPRs. The
// old wave-uniform s_load path streamed ~160 KB/CU through the ~16 KB scalar
// K$ with near-zero miss-level parallelism and forced lgkmcnt(0) drains
// (SMEM returns are unordered) — ~4.8k stall cycles per 2-e group, the entire
// 88 us plateau. LDS reads at a wave-uniform address are a hardware broadcast
// (0 bank conflicts), return IN-ORDER (precise lgkmcnt pipelining), and hit
// ~120-cycle latency. K-loop is rolled (no SGPR-pinning constraint remains),
// keeping the body ~1 KB — no I$ pressure. FMA body is identical to round 2.
// Overlap-add into 2 LDS copies, 8 serialized parity phases -> no atomics.
__global__ __launch_bounds__(512, 4) void decoder_kernel(
    const float* __restrict__ mix,    // [B,E,L]
    const float* __restrict__ mask,   // [B,C,E,L]
    const float* __restrict__ wsT,    // [E,W] transposed basis
    float* __restrict__ out)          // [B,C,T]
{
    __shared__ float4 basisS4[BFL / 4];       // 40 KB, whole basis
    __shared__ float  outS[NCP][CQ][SPAN];    // 21.1 KB
    float* basisS = (float*)basisS4;

    const int tid = threadIdx.x;
    const int ll  = tid & 63;                                  // frame lane
    const int h   = __builtin_amdgcn_readfirstlane(tid >> 6);  // e-octant, forced uniform
    const int bx  = blockIdx.x;
    const int b   = blockIdx.y;
    const int f   = TLF * bx - 1 + ll;   // may be out of [0,LQ)

    // Stage the full basis into LDS: 2560 float4s / 512 threads = 5 each.
    {
        const float4* src = (const float4*)wsT;
#pragma unroll
        for (int i = 0; i < BFL / 4 / 512; ++i)
            basisS4[tid + i * 512] = src[tid + i * 512];
    }

    // Clamp + validity multiplier keeps the K-loop branch-free.
    const int   fc    = min(max(f, 0), LQ - 1);
    const float valid = (f >= 0 && f < LQ) ? 1.0f : 0.0f;

    float acc0[WQ], acc1[WQ];
#pragma unroll
    for (int w = 0; w < WQ; ++w) { acc0[w] = 0.0f; acc1[w] = 0.0f; }

    const float* mp  = mix  + ((size_t)b * EQ + h * EH) * LQ + fc;
    const float* kp0 = mask + (((size_t)(b * CQ)) * EQ + h * EH) * LQ + fc;
    const float* kp1 = kp0 + (size_t)EQ * LQ;          // channel 1 mask
    const float* bS  = basisS + h * (EH * WQ);         // wave-uniform LDS base

    __syncthreads();   // basis staged

#pragma unroll 1
    for (int eo = 0; eo < EH; eo += 2) {
        float m0  = mp[(size_t)eo * LQ];
        float m1  = mp[(size_t)(eo + 1) * LQ];
        float k00 = kp0[(size_t)eo * LQ] * valid;
        float k01 = kp0[(size_t)(eo + 1) * LQ] * valid;
        float k10 = kp1[(size_t)eo * LQ] * valid;
        float k11 = kp1[(size_t)(eo + 1) * LQ] * valid;
        {
            float s0 = m0 * k00;
            float s1 = m0 * k10;
            const float* bb = bS + eo * WQ;        // uniform LDS -> broadcast
#pragma unroll
            for (int w = 0; w < WQ; ++w) {
                acc0[w] = fmaf(s0, bb[w], acc0[w]);
                acc1[w] = fmaf(s1, bb[w], acc1[w]);
            }
        }
        {
            float s0 = m1 * k01;
            float s1 = m1 * k11;
            const float* bb = bS + (eo + 1) * WQ;  // uniform LDS -> broadcast
#pragma unroll
            for (int w = 0; w < WQ; ++w) {
                acc0[w] = fmaf(s0, bb[w], acc0[w]);
                acc1[w] = fmaf(s1, bb[w], acc1[w]);
            }
        }
    }

    __syncthreads();   // all K-loop LDS reads done before outS overwrites? No:
                       // basisS and outS are separate arrays; this barrier just
                       // orders the parity phases below. Kept for clarity.

    // Overlap-add into LDS copy cp = h>>2. 8 serialized phases
    // ((h&3) x ll-parity); even-ll ranges [20*ll,20*ll+40) tile [0,1280)
    // exactly, so phase 0 is a plain store (no pre-zero needed; indices
    // [1280,1300) get odd-ll adds but are never read back).
    const int base = ll * STEP;
    const int cp   = h >> 2;
    const int hq   = h & 3;
    if (hq == 0 && (ll & 1) == 0) {
#pragma unroll
        for (int w = 0; w < WQ; ++w) {
            outS[cp][0][base + w] = acc0[w];
            outS[cp][1][base + w] = acc1[w];
        }
    }
    __syncthreads();
#pragma unroll
    for (int ph = 1; ph < 8; ++ph) {
        if (hq == (ph >> 1) && (ll & 1) == (ph & 1)) {
#pragma unroll
            for (int w = 0; w < WQ; ++w) {
                outS[cp][0][base + w] += acc0[w];
                outS[cp][1][base + w] += acc1[w];
            }
        }
        __syncthreads();
    }

    // Store owned span: t = 1260*bx + i  <->  outS[*][c][20 + i], i in [0,1260)
    for (int cc = 0; cc < CQ; ++cc) {
        const size_t ob = ((size_t)b * CQ + cc) * TQ + (size_t)OWN * bx;
        for (int i = tid; i < OWN; i += 512) {
            const long t = (long)OWN * bx + i;
            if (t < (long)TQ) {
                out[ob + i] = outS[0][cc][STEP + i] + outS[1][cc][STEP + i];
            }
        }
    }
}

extern "C" void kernel_launch(void* const* d_in, const int* in_sizes, int n_in,
                              void* d_out, int out_size, void* d_ws, size_t ws_size,
                              hipStream_t stream) {
    const float* mix   = (const float*)d_in[0];
    const float* mask  = (const float*)d_in[1];
    const float* basis = (const float*)d_in[2];
    float* out = (float*)d_out;
    float* wsT = (float*)d_ws;   // needs EQ*WQ*4 = 40960 bytes

    transpose_basis_kernel<<<dim3((EQ * WQ + 255) / 256), 256, 0, stream>>>(basis, wsT);

    dim3 grid(NBX, BQ);
    decoder_kernel<<<grid, 512, 0, stream>>>(mix, mask, wsT, out);
}

// Round 6
// 243.836 us; speedup vs baseline: 1.9145x; 1.9145x over previous
//
#include <hip/hip_runtime.h>

// Problem constants (fixed by setup_inputs)
#define BQ   4
#define CQ   2
#define EQ   256
#define LQ   16000
#define WQ   40
#define STEP 20
#define TQ   ((LQ - 1) * STEP + WQ)   // 320020
#define TLF  63                       // owned-frame pitch per block (64 computed, 1 overlap)
#define OWN  (TLF * STEP)             // 1260 owned output samples per block
#define NBX  254                      // 254 * 1260 = 320040 >= 320020
#define NH   4                        // e-quarters
#define EH   (EQ / NH)                // 64 e's per thread
#define SPAN (TLF * STEP + WQ + STEP) // 1320 floats per (copy, c)
#define BFL  (EQ * WQ)                // 10240 basis floats (40 KB)

// Pre-kernel: transpose basis [W][E] -> wsT [E][W] (fp32, rows contiguous)
// so the decoder can stage e-rows into LDS with coalesced float4 loads.
__global__ void transpose_basis_kernel(const float* __restrict__ basis,
                                       float* __restrict__ wsT) {
    int i = blockIdx.x * 256 + threadIdx.x;
    if (i < EQ * WQ) {
        int e = i / WQ;
        int w = i - e * WQ;
        wsT[i] = basis[w * EQ + e];
    }
}

// ROUND-0 STRUCTURE, ONE CHANGE: basis comes from LDS broadcast, not SGPRs.
// Rationale: rounds 3/4/5's pipeline experiments all spilled (WRITE_SIZE
// 228-660 MB) and were confounded; rounds 0/2 are the only clean points
// (88 us, VALU 25%, ~1 op/FMA -> instruction stream minimal, stalls ~75%).
// Hypothesis under test: the stall is the scalar basis stream (~160 KB/CU
// through the small scalar K$, unordered SMEM returns forcing lgkmcnt(0)
// drains per 2-e group). Wave-uniform ds_read is a hardware broadcast
// (conflict-free), returns in-order, ~120 cyc latency, and the compiler
// pipelines it with fine-grained lgkmcnt. Everything else is byte-identical
// to the proven round-0 kernel; acc[40] + temps fit the 128-VGPR cap of
// __launch_bounds__(512,4) with wide margin (round 0 ran at ~32 VGPR).
__global__ __launch_bounds__(512, 4) void decoder_kernel(
    const float* __restrict__ mix,    // [B,E,L]
    const float* __restrict__ mask,   // [B,C,E,L]
    const float* __restrict__ wsT,    // [E,W] transposed basis
    float* __restrict__ out)          // [B,C,T]
{
    __shared__ float4 basisS4[BFL / 4];      // 40 KB, whole basis
    __shared__ float  outS[2][CQ][SPAN];     // ~21 KB
    float* basisS = (float*)basisS4;

    const int tid = threadIdx.x;
    const int ll  = tid & 63;                                  // frame lane
    const int c   = (tid >> 6) & 1;                            // channel (wave-uniform)
    const int h   = __builtin_amdgcn_readfirstlane(tid >> 7);  // e-quarter, forced uniform
    const int bx  = blockIdx.x;
    const int b   = blockIdx.y;
    const int f   = TLF * bx - 1 + ll;   // may be out of [0,LQ)

    // Stage the full basis into LDS: 2560 float4s / 512 threads = 5 each.
    {
        const float4* src = (const float4*)wsT;
#pragma unroll
        for (int i = 0; i < BFL / 4 / 512; ++i)
            basisS4[tid + i * 512] = src[tid + i * 512];
    }

    // Clamp + validity multiplier: keeps the K-loop branch-free.
    const int   fc    = min(max(f, 0), LQ - 1);
    const float valid = (f >= 0 && f < LQ) ? 1.0f : 0.0f;

    float acc[WQ];
#pragma unroll
    for (int w = 0; w < WQ; ++w) acc[w] = 0.0f;

    const float* mp = mix  + ((size_t)b * EQ + h * EH) * LQ + fc;
    const float* kp = mask + (((size_t)(b * CQ + c)) * EQ + h * EH) * LQ + fc;
    const float* bS = basisS + h * (EH * WQ);   // wave-uniform LDS base

    __syncthreads();   // basis staged

    for (int eo = 0; eo < EH; eo += 2) {
        float m0 = mp[(size_t)eo * LQ];
        float m1 = mp[(size_t)(eo + 1) * LQ];
        float k0 = kp[(size_t)eo * LQ] * valid;
        float k1 = kp[(size_t)(eo + 1) * LQ] * valid;
        {
            float s = m0 * k0;
            const float* bb = bS + eo * WQ;        // uniform LDS -> broadcast
#pragma unroll
            for (int w = 0; w < WQ; ++w) acc[w] = fmaf(s, bb[w], acc[w]);
        }
        {
            float s = m1 * k1;
            const float* bb = bS + (eo + 1) * WQ;  // uniform LDS -> broadcast
#pragma unroll
            for (int w = 0; w < WQ; ++w) acc[w] = fmaf(s, bb[w], acc[w]);
        }
    }

    // Overlap-add into LDS copy cp = h>>1. 4 serialized parity phases
    // (h-parity x ll-parity); even-ll ranges [20*ll,20*ll+40) tile [0,1280)
    // exactly, so phase 0 is a plain store (no pre-zero needed; indices
    // [1280,1300) are written by odd-ll adds but never read back).
    const int base = ll * STEP;
    const int cp   = h >> 1;
    const int hp   = h & 1;
    if (hp == 0 && (ll & 1) == 0) {
#pragma unroll
        for (int w = 0; w < WQ; ++w) outS[cp][c][base + w] = acc[w];
    }
    __syncthreads();
    if (hp == 0 && (ll & 1) == 1) {
#pragma unroll
        for (int w = 0; w < WQ; ++w) outS[cp][c][base + w] += acc[w];
    }
    __syncthreads();
    if (hp == 1 && (ll & 1) == 0) {
#pragma unroll
        for (int w = 0; w < WQ; ++w) outS[cp][c][base + w] += acc[w];
    }
    __syncthreads();
    if (hp == 1 && (ll & 1) == 1) {
#pragma unroll
        for (int w = 0; w < WQ; ++w) outS[cp][c][base + w] += acc[w];
    }
    __syncthreads();

    // Store owned span: t = 1260*bx + i  <->  outS[*][c][20 + i], i in [0,1260)
    for (int cc = 0; cc < CQ; ++cc) {
        const size_t ob = ((size_t)b * CQ + cc) * TQ + (size_t)OWN * bx;
        for (int i = tid; i < OWN; i += 512) {
            const long t = (long)OWN * bx + i;
            if (t < (long)TQ) {
                out[ob + i] = outS[0][cc][STEP + i] + outS[1][cc][STEP + i];
            }
        }
    }
}

extern "C" void kernel_launch(void* const* d_in, const int* in_sizes, int n_in,
                              void* d_out, int out_size, void* d_ws, size_t ws_size,
                              hipStream_t stream) {
    const float* mix   = (const float*)d_in[0];
    const float* mask  = (const float*)d_in[1];
    const float* basis = (const float*)d_in[2];
    float* out = (float*)d_out;
    float* wsT = (float*)d_ws;   // needs EQ*WQ*4 = 40960 bytes

    transpose_basis_kernel<<<dim3((EQ * WQ + 255) / 256), 256, 0, stream>>>(basis, wsT);

    dim3 grid(NBX, BQ);
    decoder_kernel<<<grid, 512, 0, stream>>>(mix, mask, wsT, out);
}